// Round 1
// baseline (720.231 us; speedup 1.0000x reference)
//
#include <hip/hip_runtime.h>
#include <hip/hip_bf16.h>

// Problem dims
#define NTOK 8192       // B*T
#define NASN 16384      // NTOK * K(=2)
#define C_ 512
#define H_ 2048
#define E_ 8
#define MAXT 136        // max total 128-row m-tiles: 16384/128 + 7 rounding = 135

typedef __bf16 bf16x8 __attribute__((ext_vector_type(8)));
typedef float f32x4 __attribute__((ext_vector_type(4)));

// Workspace layout (bytes). Total ~117.7 MB.
#define WS_COUNTS 0
#define WS_CURS   256
#define WS_OFFS   512
#define WS_T1S    768
#define WS_INFO   1024                         // NTOK * 16 (int4 per token)
#define WS_TOKL   (WS_INFO + NTOK*16)          // NASN * 4
#define WS_GATE   (WS_TOKL + NASN*4)           // NASN * 4
#define WS_XG     (WS_GATE + NASN*4)           // NASN*C_*2 bf16 gathered X
#define WS_W1B    (WS_XG + (size_t)NASN*C_*2)  // E*H*C bf16, layout [e][h][c]
#define WS_W2B    (WS_W1B + (size_t)E_*H_*C_*2)// E*C*H bf16, layout [e][c][h]
#define WS_HS     (WS_W2B + (size_t)E_*H_*C_*2)// NASN*H bf16 hidden acts

__device__ __forceinline__ unsigned int f2bf(float f) {
  __hip_bfloat16 h = __float2bfloat16(f);
  return (unsigned int)*(unsigned short*)&h;
}

// ---------------- router: one wave per token, fp32 ----------------
__global__ __launch_bounds__(256) void k_router(
    const float* __restrict__ x, const float* __restrict__ Wr,
    const float* __restrict__ br, float* __restrict__ out_logits,
    float* __restrict__ out_idx, int4* __restrict__ info,
    int* __restrict__ counts)
{
  int t = blockIdx.x * 4 + (threadIdx.x >> 6);
  int lane = threadIdx.x & 63;
  const float4* xr = (const float4*)(x + (size_t)t * C_);
  float4 x0 = xr[lane*2], x1 = xr[lane*2+1];
  float xs[8] = {x0.x,x0.y,x0.z,x0.w,x1.x,x1.y,x1.z,x1.w};
  float acc[8] = {0,0,0,0,0,0,0,0};
  #pragma unroll
  for (int j = 0; j < 8; j++) {
    const float4* w = (const float4*)(Wr + (size_t)(lane*8+j) * E_);
    float4 w0 = w[0], w1 = w[1];
    float we[8] = {w0.x,w0.y,w0.z,w0.w,w1.x,w1.y,w1.z,w1.w};
    #pragma unroll
    for (int e = 0; e < 8; e++) acc[e] += xs[j] * we[e];
  }
  #pragma unroll
  for (int off = 1; off < 64; off <<= 1) {
    #pragma unroll
    for (int e = 0; e < 8; e++) acc[e] += __shfl_xor(acc[e], off, 64);
  }
  #pragma unroll
  for (int e = 0; e < 8; e++) acc[e] += br[e];
  if (lane == 0) {
    #pragma unroll
    for (int e = 0; e < 8; e++) out_logits[t*8 + e] = acc[e];
    // top-2, ties -> lowest index (jax.lax.top_k semantics)
    int i0 = 0; float v0 = acc[0];
    #pragma unroll
    for (int e = 1; e < 8; e++) if (acc[e] > v0) { v0 = acc[e]; i0 = e; }
    int i1 = -1; float v1 = -1e30f;
    #pragma unroll
    for (int e = 0; e < 8; e++) if (e != i0 && acc[e] > v1) { v1 = acc[e]; i1 = e; }
    float d = expf(v1 - v0);          // <= 0 -> stable
    float s1 = d / (1.0f + d);
    float s0 = 1.0f - s1;
    out_idx[t*2]     = (float)i0;     // int indices stored as float values
    out_idx[t*2 + 1] = (float)i1;
    info[t] = make_int4(i0, i1, __float_as_int(s0), __float_as_int(s1));
    atomicAdd(&counts[i0], 1);
    atomicAdd(&counts[i1], 1);
  }
}

// ---------------- prefix: offsets, cursors, tile table ----------------
__global__ void k_prefix(const int* __restrict__ counts, int* __restrict__ curs,
                         int* __restrict__ offs, int* __restrict__ t1s)
{
  if (threadIdx.x == 0) {
    int o = 0, t = 0;
    offs[0] = 0; t1s[0] = 0;
    for (int e = 0; e < 8; e++) {
      curs[e] = o;
      o += counts[e];
      offs[e+1] = o;
      t += (counts[e] + 127) >> 7;
      t1s[e+1] = t;
    }
  }
}

// ---------------- scatter: slot assign + gather x -> bf16 ----------------
__global__ __launch_bounds__(256) void k_scatter(
    const float* __restrict__ x, const int4* __restrict__ info,
    int* __restrict__ curs, int* __restrict__ tokl, float* __restrict__ gate,
    unsigned short* __restrict__ Xg)
{
  int t = blockIdx.x * 4 + (threadIdx.x >> 6);
  int lane = threadIdx.x & 63;
  int slot0 = 0, slot1 = 0;
  if (lane == 0) {
    int4 nfo = info[t];
    slot0 = atomicAdd(&curs[nfo.x], 1);
    slot1 = atomicAdd(&curs[nfo.y], 1);
    tokl[slot0] = t; gate[slot0] = __int_as_float(nfo.z);
    tokl[slot1] = t; gate[slot1] = __int_as_float(nfo.w);
  }
  slot0 = __shfl(slot0, 0, 64);
  slot1 = __shfl(slot1, 0, 64);
  const float4* xr = (const float4*)(x + (size_t)t * C_);
  float4 x0 = xr[lane*2], x1 = xr[lane*2+1];
  unsigned int p0 = f2bf(x0.x) | (f2bf(x0.y) << 16);
  unsigned int p1 = f2bf(x0.z) | (f2bf(x0.w) << 16);
  unsigned int p2 = f2bf(x1.x) | (f2bf(x1.y) << 16);
  unsigned int p3 = f2bf(x1.z) | (f2bf(x1.w) << 16);
  uint4 pk; pk.x = p0; pk.y = p1; pk.z = p2; pk.w = p3;
  *(uint4*)(Xg + (size_t)slot0 * C_ + lane*8) = pk;
  *(uint4*)(Xg + (size_t)slot1 * C_ + lane*8) = pk;
}

// ---------------- weight transpose fp32[R][S] -> bf16[S][R] ----------------
__global__ __launch_bounds__(256) void k_transpose(
    const float* __restrict__ in, unsigned short* __restrict__ outp, int R, int S)
{
  __shared__ float tile[32][33];
  size_t zo = (size_t)blockIdx.z * R * S;
  in += zo; outp += zo;
  int s0 = blockIdx.x * 32, r0 = blockIdx.y * 32;
  int tx = threadIdx.x, ty = threadIdx.y;
  #pragma unroll
  for (int i = 0; i < 4; i++)
    tile[ty + i*8][tx] = in[(size_t)(r0 + ty + i*8) * S + s0 + tx];
  __syncthreads();
  #pragma unroll
  for (int i = 0; i < 4; i++)
    outp[(size_t)(s0 + ty + i*8) * R + r0 + tx] = f2bf(tile[tx][ty + i*8]);
}

// ---------------- grouped GEMM layer 1: H = relu(Xg @ W1 + b1) ----------------
// grid (16 n-tiles, MAXT m-tiles), block 256 = 4 waves, tile 128x128, K=512
__global__ __launch_bounds__(256) void k_gemm1(
    const unsigned short* __restrict__ Xg, const unsigned short* __restrict__ W1b,
    const float* __restrict__ b1, unsigned short* __restrict__ Hs,
    const int* __restrict__ offs, const int* __restrict__ t1s)
{
  __shared__ __align__(16) unsigned short Al[128*72];  // +8 bf16 pad: 2-way max conflict
  __shared__ __align__(16) unsigned short Bl[128*72];
  int mt = blockIdx.y;
  if (mt >= t1s[8]) return;
  int e = 0;
  #pragma unroll
  for (int i = 0; i < 7; i++) if (mt >= t1s[e+1]) e++;
  int row0 = offs[e] + (mt - t1s[e]) * 128;
  int rowEnd = offs[e+1];
  int n0 = blockIdx.x * 128;
  int tid = threadIdx.x, lane = tid & 63, w = tid >> 6;
  int wm = (w & 1) * 64, wn = (w >> 1) * 64;
  int quad = lane >> 4, l16 = lane & 15;
  const f32x4 zero = {0.f, 0.f, 0.f, 0.f};
  f32x4 acc[4][4];
  #pragma unroll
  for (int i = 0; i < 4; i++)
    #pragma unroll
    for (int j = 0; j < 4; j++) acc[i][j] = zero;
  const unsigned short* Bsrc = W1b + ((size_t)e * H_ + n0) * C_;
  int ar = tid >> 3, ac = (tid & 7) * 8;
  for (int kk = 0; kk < C_; kk += 64) {
    #pragma unroll
    for (int it = 0; it < 4; it++) {
      int r = ar + it * 32;
      int gr = row0 + r; gr = gr < NASN-1 ? gr : NASN-1;   // clamp tile overhang
      *(uint4*)&Al[r*72 + ac] = *(const uint4*)(Xg + (size_t)gr * C_ + kk + ac);
      *(uint4*)&Bl[r*72 + ac] = *(const uint4*)(Bsrc + (size_t)r * C_ + kk + ac);
    }
    __syncthreads();
    #pragma unroll
    for (int ks = 0; ks < 64; ks += 32) {
      bf16x8 af[4], bfr[4];
      #pragma unroll
      for (int i = 0; i < 4; i++)
        af[i] = *(const bf16x8*)&Al[(wm + i*16 + l16)*72 + ks + quad*8];
      #pragma unroll
      for (int j = 0; j < 4; j++)
        bfr[j] = *(const bf16x8*)&Bl[(wn + j*16 + l16)*72 + ks + quad*8];
      #pragma unroll
      for (int i = 0; i < 4; i++)
        #pragma unroll
        for (int j = 0; j < 4; j++)
          acc[i][j] = __builtin_amdgcn_mfma_f32_16x16x32_bf16(af[i], bfr[j], acc[i][j], 0, 0, 0);
    }
    __syncthreads();
  }
  #pragma unroll
  for (int j = 0; j < 4; j++) {
    int n = n0 + wn + j*16 + l16;
    float bias = b1[e * H_ + n];
    #pragma unroll
    for (int i = 0; i < 4; i++) {
      int mbase = row0 + wm + i*16 + quad*4;
      #pragma unroll
      for (int r = 0; r < 4; r++) {
        int m = mbase + r;
        if (m < rowEnd) {
          float v = acc[i][j][r] + bias;
          Hs[(size_t)m * H_ + n] = f2bf(v > 0.f ? v : 0.f);
        }
      }
    }
  }
}

// ---------------- grouped GEMM layer 2: out += gate*(Hs @ W2 + b2) ----------------
// grid (4 n-tiles, MAXT m-tiles), K=2048
__global__ __launch_bounds__(256) void k_gemm2(
    const unsigned short* __restrict__ Hs, const unsigned short* __restrict__ W2b,
    const float* __restrict__ b2, const int* __restrict__ tokl,
    const float* __restrict__ gate, float* __restrict__ outp,
    const int* __restrict__ offs, const int* __restrict__ t1s)
{
  __shared__ __align__(16) unsigned short Al[128*72];
  __shared__ __align__(16) unsigned short Bl[128*72];
  int mt = blockIdx.y;
  if (mt >= t1s[8]) return;
  int e = 0;
  #pragma unroll
  for (int i = 0; i < 7; i++) if (mt >= t1s[e+1]) e++;
  int row0 = offs[e] + (mt - t1s[e]) * 128;
  int rowEnd = offs[e+1];
  int n0 = blockIdx.x * 128;
  int tid = threadIdx.x, lane = tid & 63, w = tid >> 6;
  int wm = (w & 1) * 64, wn = (w >> 1) * 64;
  int quad = lane >> 4, l16 = lane & 15;
  const f32x4 zero = {0.f, 0.f, 0.f, 0.f};
  f32x4 acc[4][4];
  #pragma unroll
  for (int i = 0; i < 4; i++)
    #pragma unroll
    for (int j = 0; j < 4; j++) acc[i][j] = zero;
  const unsigned short* Bsrc = W2b + ((size_t)e * C_ + n0) * H_;
  int ar = tid >> 3, ac = (tid & 7) * 8;
  for (int kk = 0; kk < H_; kk += 64) {
    #pragma unroll
    for (int it = 0; it < 4; it++) {
      int r = ar + it * 32;
      int gr = row0 + r; gr = gr < NASN-1 ? gr : NASN-1;
      *(uint4*)&Al[r*72 + ac] = *(const uint4*)(Hs + (size_t)gr * H_ + kk + ac);
      *(uint4*)&Bl[r*72 + ac] = *(const uint4*)(Bsrc + (size_t)r * H_ + kk + ac);
    }
    __syncthreads();
    #pragma unroll
    for (int ks = 0; ks < 64; ks += 32) {
      bf16x8 af[4], bfr[4];
      #pragma unroll
      for (int i = 0; i < 4; i++)
        af[i] = *(const bf16x8*)&Al[(wm + i*16 + l16)*72 + ks + quad*8];
      #pragma unroll
      for (int j = 0; j < 4; j++)
        bfr[j] = *(const bf16x8*)&Bl[(wn + j*16 + l16)*72 + ks + quad*8];
      #pragma unroll
      for (int i = 0; i < 4; i++)
        #pragma unroll
        for (int j = 0; j < 4; j++)
          acc[i][j] = __builtin_amdgcn_mfma_f32_16x16x32_bf16(af[i], bfr[j], acc[i][j], 0, 0, 0);
    }
    __syncthreads();
  }
  #pragma unroll
  for (int j = 0; j < 4; j++) {
    int n = n0 + wn + j*16 + l16;
    float bias = b2[e * C_ + n];
    #pragma unroll
    for (int i = 0; i < 4; i++) {
      int mbase = row0 + wm + i*16 + quad*4;
      #pragma unroll
      for (int r = 0; r < 4; r++) {
        int m = mbase + r;
        if (m < rowEnd) {
          int tok = tokl[m];
          float g = gate[m];
          atomicAdd(outp + (size_t)tok * C_ + n, (acc[i][j][r] + bias) * g);
        }
      }
    }
  }
}

extern "C" void kernel_launch(void* const* d_in, const int* in_sizes, int n_in,
                              void* d_out, int out_size, void* d_ws, size_t ws_size,
                              hipStream_t stream)
{
  const float* x  = (const float*)d_in[0];
  const float* Wr = (const float*)d_in[1];
  const float* br = (const float*)d_in[2];
  const float* W1 = (const float*)d_in[3];
  const float* b1 = (const float*)d_in[4];
  const float* W2 = (const float*)d_in[5];
  const float* b2 = (const float*)d_in[6];
  float* out = (float*)d_out;                 // [logits 65536 | idx 16384 | out 4194304]
  char* ws = (char*)d_ws;

  int* counts = (int*)(ws + WS_COUNTS);
  int* curs   = (int*)(ws + WS_CURS);
  int* offs   = (int*)(ws + WS_OFFS);
  int* t1s    = (int*)(ws + WS_T1S);
  int4* info  = (int4*)(ws + WS_INFO);
  int* tokl   = (int*)(ws + WS_TOKL);
  float* gate = (float*)(ws + WS_GATE);
  unsigned short* Xg  = (unsigned short*)(ws + WS_XG);
  unsigned short* W1b = (unsigned short*)(ws + WS_W1B);
  unsigned short* W2b = (unsigned short*)(ws + WS_W2B);
  unsigned short* Hs  = (unsigned short*)(ws + WS_HS);

  hipMemsetAsync(counts, 0, 32, stream);
  hipMemsetAsync(out + 81920, 0, (size_t)NTOK * C_ * sizeof(float), stream);

  k_transpose<<<dim3(H_/32, C_/32, E_), dim3(32, 8), 0, stream>>>(W1, W1b, C_, H_);
  k_transpose<<<dim3(C_/32, H_/32, E_), dim3(32, 8), 0, stream>>>(W2, W2b, H_, C_);
  k_router<<<NTOK/4, 256, 0, stream>>>(x, Wr, br, out, out + 65536, info, counts);
  k_prefix<<<1, 64, 0, stream>>>(counts, curs, offs, t1s);
  k_scatter<<<NTOK/4, 256, 0, stream>>>(x, info, curs, tokl, gate, Xg);
  k_gemm1<<<dim3(16, MAXT), 256, 0, stream>>>(Xg, W1b, b1, Hs, offs, t1s);
  k_gemm2<<<dim3(4, MAXT), 256, 0, stream>>>(Hs, W2b, b2, tokl, gate, out + 81920, offs, t1s);
}

// Round 2
// 321.450 us; speedup vs baseline: 2.2406x; 2.2406x over previous
//
#include <hip/hip_runtime.h>
#include <hip/hip_bf16.h>

// Problem dims
#define NTOK 8192       // B*T
#define NASN 16384      // NTOK * K(=2)
#define C_ 512
#define H_ 2048
#define E_ 8
#define NCH 128         // token chunks for atomic spreading
#define CHTOK 64        // tokens per chunk
#define MAXT 136        // max total 128-row m-tiles

typedef __bf16 bf16x8 __attribute__((ext_vector_type(8)));
typedef float f32x4 __attribute__((ext_vector_type(4)));

// Workspace layout (bytes). Total ~118 MB.
#define WS_COUNTS 0                              // NCH*8*4 = 4096
#define WS_BASE   4096                           // NCH*8*4 = 4096
#define WS_OFFS   8192                           // 9*4 -> pad 256
#define WS_T1S    8448                           // 9*4 -> pad 256
#define WS_INFO   8704                           // NTOK*16
#define WS_TOKL   (WS_INFO + NTOK*16)            // NASN*4
#define WS_GATE   (WS_TOKL + NASN*4)             // NASN*4
#define WS_SLOTS  (WS_GATE + NASN*4)             // NTOK*8 (int2)
#define WS_XG     (WS_SLOTS + NTOK*8)            // NASN*C_*2 bf16 gathered X
#define WS_W1B    (WS_XG + (size_t)NASN*C_*2)    // E*H*C bf16, [e][h][c]
#define WS_W2B    (WS_W1B + (size_t)E_*H_*C_*2)  // E*C*H bf16, [e][c][h]
#define WS_HS     (WS_W2B + (size_t)E_*H_*C_*2)  // NASN*H bf16 hidden acts
// Ys (NASN*C_*4 = 33.55 MB) aliases [WS_XG .. WS_XG+33.55MB) = Xg+W1b,
// both dead by the time k_gemm2 runs (sequential stream).
#define WS_YS     WS_XG

__device__ __forceinline__ unsigned int f2bf(float f) {
  __hip_bfloat16 h = __float2bfloat16(f);
  return (unsigned int)*(unsigned short*)&h;
}

// ---------------- router: one wave per token, fp32 ----------------
__global__ __launch_bounds__(256) void k_router(
    const float* __restrict__ x, const float* __restrict__ Wr,
    const float* __restrict__ br, float* __restrict__ out_logits,
    float* __restrict__ out_idx, int4* __restrict__ info,
    int* __restrict__ counts)
{
  int t = blockIdx.x * 4 + (threadIdx.x >> 6);
  int lane = threadIdx.x & 63;
  const float4* xr = (const float4*)(x + (size_t)t * C_);
  float4 x0 = xr[lane*2], x1 = xr[lane*2+1];
  float xs[8] = {x0.x,x0.y,x0.z,x0.w,x1.x,x1.y,x1.z,x1.w};
  float acc[8] = {0,0,0,0,0,0,0,0};
  #pragma unroll
  for (int j = 0; j < 8; j++) {
    const float4* w = (const float4*)(Wr + (size_t)(lane*8+j) * E_);
    float4 w0 = w[0], w1 = w[1];
    float we[8] = {w0.x,w0.y,w0.z,w0.w,w1.x,w1.y,w1.z,w1.w};
    #pragma unroll
    for (int e = 0; e < 8; e++) acc[e] += xs[j] * we[e];
  }
  #pragma unroll
  for (int off = 1; off < 64; off <<= 1) {
    #pragma unroll
    for (int e = 0; e < 8; e++) acc[e] += __shfl_xor(acc[e], off, 64);
  }
  #pragma unroll
  for (int e = 0; e < 8; e++) acc[e] += br[e];
  if (lane == 0) {
    #pragma unroll
    for (int e = 0; e < 8; e++) out_logits[t*8 + e] = acc[e];
    int i0 = 0; float v0 = acc[0];
    #pragma unroll
    for (int e = 1; e < 8; e++) if (acc[e] > v0) { v0 = acc[e]; i0 = e; }
    int i1 = -1; float v1 = -1e30f;
    #pragma unroll
    for (int e = 0; e < 8; e++) if (e != i0 && acc[e] > v1) { v1 = acc[e]; i1 = e; }
    float d = expf(v1 - v0);
    float s1 = d / (1.0f + d);
    float s0 = 1.0f - s1;
    out_idx[t*2]     = (float)i0;
    out_idx[t*2 + 1] = (float)i1;
    info[t] = make_int4(i0, i1, __float_as_int(s0), __float_as_int(s1));
    int ch = t >> 6;   // CHTOK=64
    atomicAdd(&counts[ch*8 + i0], 1);   // spread over 1024 counters
    atomicAdd(&counts[ch*8 + i1], 1);
  }
}

// ---------------- prefix: per-chunk/per-expert slot bases ----------------
__global__ __launch_bounds__(256) void k_prefix(
    const int* __restrict__ counts, int* __restrict__ base,
    int* __restrict__ offs, int* __restrict__ t1s)
{
  __shared__ int lc[NCH*8];
  __shared__ int tot[8];
  __shared__ int off_s[9];
  int tid = threadIdx.x;
  for (int i = tid; i < NCH*8; i += 256) lc[i] = counts[i];
  __syncthreads();
  if (tid < 8) {
    int run = 0;
    for (int c = 0; c < NCH; c++) { int v = lc[c*8+tid]; lc[c*8+tid] = run; run += v; }
    tot[tid] = run;
  }
  __syncthreads();
  if (tid == 0) {
    int o = 0, t = 0;
    off_s[0] = 0; offs[0] = 0; t1s[0] = 0;
    for (int e = 0; e < 8; e++) {
      o += tot[e];
      off_s[e+1] = o; offs[e+1] = o;
      t += (tot[e] + 127) >> 7;
      t1s[e+1] = t;
    }
  }
  __syncthreads();
  for (int i = tid; i < NCH*8; i += 256) base[i] = off_s[i & 7] + lc[i];
}

// ---------------- scatter: chunk-local LDS rank -> slots ----------------
__global__ __launch_bounds__(64) void k_scatter(
    const int4* __restrict__ info, const int* __restrict__ base,
    int* __restrict__ tokl, float* __restrict__ gate, int2* __restrict__ slots2)
{
  __shared__ int cur[8];
  int c = blockIdx.x, tid = threadIdx.x;
  if (tid < 8) cur[tid] = base[c*8 + tid];
  __syncthreads();
  int t = c * CHTOK + tid;
  int4 nfo = info[t];
  int r0 = atomicAdd(&cur[nfo.x], 1);
  int r1 = atomicAdd(&cur[nfo.y], 1);
  tokl[r0] = t; gate[r0] = __int_as_float(nfo.z);
  tokl[r1] = t; gate[r1] = __int_as_float(nfo.w);
  slots2[t] = make_int2(r0, r1);
}

// ---------------- gather: x rows -> bf16 Xg rows, one wave per row ----------------
__global__ __launch_bounds__(256) void k_gather(
    const float* __restrict__ x, const int* __restrict__ tokl,
    unsigned short* __restrict__ Xg)
{
  int slot = blockIdx.x * 4 + (threadIdx.x >> 6);
  int lane = threadIdx.x & 63;
  int t = tokl[slot];
  const float4* xr = (const float4*)(x + (size_t)t * C_);
  float4 x0 = xr[lane*2], x1 = xr[lane*2+1];
  uint4 pk;
  pk.x = f2bf(x0.x) | (f2bf(x0.y) << 16);
  pk.y = f2bf(x0.z) | (f2bf(x0.w) << 16);
  pk.z = f2bf(x1.x) | (f2bf(x1.y) << 16);
  pk.w = f2bf(x1.z) | (f2bf(x1.w) << 16);
  *(uint4*)(Xg + (size_t)slot * C_ + lane*8) = pk;
}

// ---------------- weight transpose fp32[R][S] -> bf16[S][R] ----------------
__global__ __launch_bounds__(256) void k_transpose(
    const float* __restrict__ in, unsigned short* __restrict__ outp, int R, int S)
{
  __shared__ float tile[32][33];
  size_t zo = (size_t)blockIdx.z * R * S;
  in += zo; outp += zo;
  int s0 = blockIdx.x * 32, r0 = blockIdx.y * 32;
  int tx = threadIdx.x, ty = threadIdx.y;
  #pragma unroll
  for (int i = 0; i < 4; i++)
    tile[ty + i*8][tx] = in[(size_t)(r0 + ty + i*8) * S + s0 + tx];
  __syncthreads();
  #pragma unroll
  for (int i = 0; i < 4; i++)
    outp[(size_t)(s0 + ty + i*8) * R + r0 + tx] = f2bf(tile[tx][ty + i*8]);
}

// ---------------- grouped GEMM layer 1: Hs = relu(Xg @ W1 + b1) ----------------
__global__ __launch_bounds__(256) void k_gemm1(
    const unsigned short* __restrict__ Xg, const unsigned short* __restrict__ W1b,
    const float* __restrict__ b1, unsigned short* __restrict__ Hs,
    const int* __restrict__ offs, const int* __restrict__ t1s)
{
  __shared__ __align__(16) unsigned short Al[128*72];  // +8 pad: <=2-way conflict
  __shared__ __align__(16) unsigned short Bl[128*72];
  int mt = blockIdx.y;
  if (mt >= t1s[8]) return;
  int e = 0;
  #pragma unroll
  for (int i = 0; i < 7; i++) if (mt >= t1s[e+1]) e++;
  int row0 = offs[e] + (mt - t1s[e]) * 128;
  int rowEnd = offs[e+1];
  int n0 = blockIdx.x * 128;
  int tid = threadIdx.x, lane = tid & 63, w = tid >> 6;
  int wm = (w & 1) * 64, wn = (w >> 1) * 64;
  int quad = lane >> 4, l16 = lane & 15;
  const f32x4 zero = {0.f, 0.f, 0.f, 0.f};
  f32x4 acc[4][4];
  #pragma unroll
  for (int i = 0; i < 4; i++)
    #pragma unroll
    for (int j = 0; j < 4; j++) acc[i][j] = zero;
  const unsigned short* Bsrc = W1b + ((size_t)e * H_ + n0) * C_;
  int ar = tid >> 3, ac = (tid & 7) * 8;
  for (int kk = 0; kk < C_; kk += 64) {
    #pragma unroll
    for (int it = 0; it < 4; it++) {
      int r = ar + it * 32;
      int gr = row0 + r; gr = gr < NASN-1 ? gr : NASN-1;
      *(uint4*)&Al[r*72 + ac] = *(const uint4*)(Xg + (size_t)gr * C_ + kk + ac);
      *(uint4*)&Bl[r*72 + ac] = *(const uint4*)(Bsrc + (size_t)r * C_ + kk + ac);
    }
    __syncthreads();
    #pragma unroll
    for (int ks = 0; ks < 64; ks += 32) {
      bf16x8 af[4], bfr[4];
      #pragma unroll
      for (int i = 0; i < 4; i++)
        af[i] = *(const bf16x8*)&Al[(wm + i*16 + l16)*72 + ks + quad*8];
      #pragma unroll
      for (int j = 0; j < 4; j++)
        bfr[j] = *(const bf16x8*)&Bl[(wn + j*16 + l16)*72 + ks + quad*8];
      #pragma unroll
      for (int i = 0; i < 4; i++)
        #pragma unroll
        for (int j = 0; j < 4; j++)
          acc[i][j] = __builtin_amdgcn_mfma_f32_16x16x32_bf16(af[i], bfr[j], acc[i][j], 0, 0, 0);
    }
    __syncthreads();
  }
  #pragma unroll
  for (int j = 0; j < 4; j++) {
    int n = n0 + wn + j*16 + l16;
    float bias = b1[e * H_ + n];
    #pragma unroll
    for (int i = 0; i < 4; i++) {
      int mbase = row0 + wm + i*16 + quad*4;
      #pragma unroll
      for (int r = 0; r < 4; r++) {
        int m = mbase + r;
        if (m < rowEnd) {
          float v = acc[i][j][r] + bias;
          Hs[(size_t)m * H_ + n] = f2bf(v > 0.f ? v : 0.f);
        }
      }
    }
  }
}

// ---------------- grouped GEMM layer 2: Ys = Hs @ W2 + b2 (plain stores) ----------------
__global__ __launch_bounds__(256) void k_gemm2(
    const unsigned short* __restrict__ Hs, const unsigned short* __restrict__ W2b,
    const float* __restrict__ b2, float* __restrict__ Ys,
    const int* __restrict__ offs, const int* __restrict__ t1s)
{
  __shared__ __align__(16) unsigned short Al[128*72];
  __shared__ __align__(16) unsigned short Bl[128*72];
  int mt = blockIdx.y;
  if (mt >= t1s[8]) return;
  int e = 0;
  #pragma unroll
  for (int i = 0; i < 7; i++) if (mt >= t1s[e+1]) e++;
  int row0 = offs[e] + (mt - t1s[e]) * 128;
  int rowEnd = offs[e+1];
  int n0 = blockIdx.x * 128;
  int tid = threadIdx.x, lane = tid & 63, w = tid >> 6;
  int wm = (w & 1) * 64, wn = (w >> 1) * 64;
  int quad = lane >> 4, l16 = lane & 15;
  const f32x4 zero = {0.f, 0.f, 0.f, 0.f};
  f32x4 acc[4][4];
  #pragma unroll
  for (int i = 0; i < 4; i++)
    #pragma unroll
    for (int j = 0; j < 4; j++) acc[i][j] = zero;
  const unsigned short* Bsrc = W2b + ((size_t)e * C_ + n0) * H_;
  int ar = tid >> 3, ac = (tid & 7) * 8;
  for (int kk = 0; kk < H_; kk += 64) {
    #pragma unroll
    for (int it = 0; it < 4; it++) {
      int r = ar + it * 32;
      int gr = row0 + r; gr = gr < NASN-1 ? gr : NASN-1;
      *(uint4*)&Al[r*72 + ac] = *(const uint4*)(Hs + (size_t)gr * H_ + kk + ac);
      *(uint4*)&Bl[r*72 + ac] = *(const uint4*)(Bsrc + (size_t)r * H_ + kk + ac);
    }
    __syncthreads();
    #pragma unroll
    for (int ks = 0; ks < 64; ks += 32) {
      bf16x8 af[4], bfr[4];
      #pragma unroll
      for (int i = 0; i < 4; i++)
        af[i] = *(const bf16x8*)&Al[(wm + i*16 + l16)*72 + ks + quad*8];
      #pragma unroll
      for (int j = 0; j < 4; j++)
        bfr[j] = *(const bf16x8*)&Bl[(wn + j*16 + l16)*72 + ks + quad*8];
      #pragma unroll
      for (int i = 0; i < 4; i++)
        #pragma unroll
        for (int j = 0; j < 4; j++)
          acc[i][j] = __builtin_amdgcn_mfma_f32_16x16x32_bf16(af[i], bfr[j], acc[i][j], 0, 0, 0);
    }
    __syncthreads();
  }
  #pragma unroll
  for (int j = 0; j < 4; j++) {
    int n = n0 + wn + j*16 + l16;
    float bias = b2[e * C_ + n];
    #pragma unroll
    for (int i = 0; i < 4; i++) {
      int mbase = row0 + wm + i*16 + quad*4;
      #pragma unroll
      for (int r = 0; r < 4; r++) {
        int m = mbase + r;
        if (m < rowEnd)
          Ys[(size_t)m * C_ + n] = acc[i][j][r] + bias;
      }
    }
  }
}

// ---------------- combine: out[t] = g0*Ys[s0] + g1*Ys[s1] ----------------
__global__ __launch_bounds__(256) void k_combine(
    const float* __restrict__ Ys, const int4* __restrict__ info,
    const int2* __restrict__ slots2, float* __restrict__ outp)
{
  int t = blockIdx.x * 4 + (threadIdx.x >> 6);
  int lane = threadIdx.x & 63;
  int4 nfo = info[t];
  int2 ss = slots2[t];
  float g0 = __int_as_float(nfo.z), g1 = __int_as_float(nfo.w);
  const float4* ya = (const float4*)(Ys + (size_t)ss.x * C_);
  const float4* yb = (const float4*)(Ys + (size_t)ss.y * C_);
  float4* o = (float4*)(outp + (size_t)t * C_);
  #pragma unroll
  for (int i = 0; i < 2; i++) {
    float4 a = ya[lane*2 + i], b = yb[lane*2 + i];
    float4 r;
    r.x = g0*a.x + g1*b.x; r.y = g0*a.y + g1*b.y;
    r.z = g0*a.z + g1*b.z; r.w = g0*a.w + g1*b.w;
    o[lane*2 + i] = r;
  }
}

extern "C" void kernel_launch(void* const* d_in, const int* in_sizes, int n_in,
                              void* d_out, int out_size, void* d_ws, size_t ws_size,
                              hipStream_t stream)
{
  const float* x  = (const float*)d_in[0];
  const float* Wr = (const float*)d_in[1];
  const float* br = (const float*)d_in[2];
  const float* W1 = (const float*)d_in[3];
  const float* b1 = (const float*)d_in[4];
  const float* W2 = (const float*)d_in[5];
  const float* b2 = (const float*)d_in[6];
  float* out = (float*)d_out;   // [logits 65536 | idx 16384 | out 4194304]
  char* ws = (char*)d_ws;

  int*  counts = (int*)(ws + WS_COUNTS);
  int*  base   = (int*)(ws + WS_BASE);
  int*  offs   = (int*)(ws + WS_OFFS);
  int*  t1s    = (int*)(ws + WS_T1S);
  int4* info   = (int4*)(ws + WS_INFO);
  int*  tokl   = (int*)(ws + WS_TOKL);
  float* gate  = (float*)(ws + WS_GATE);
  int2* slots2 = (int2*)(ws + WS_SLOTS);
  unsigned short* Xg  = (unsigned short*)(ws + WS_XG);
  unsigned short* W1b = (unsigned short*)(ws + WS_W1B);
  unsigned short* W2b = (unsigned short*)(ws + WS_W2B);
  unsigned short* Hs  = (unsigned short*)(ws + WS_HS);
  float* Ys = (float*)(ws + WS_YS);   // aliases Xg+W1b (dead by gemm2)

  hipMemsetAsync(counts, 0, NCH*8*sizeof(int), stream);

  k_transpose<<<dim3(H_/32, C_/32, E_), dim3(32, 8), 0, stream>>>(W1, W1b, C_, H_);
  k_transpose<<<dim3(C_/32, H_/32, E_), dim3(32, 8), 0, stream>>>(W2, W2b, H_, C_);
  k_router<<<NTOK/4, 256, 0, stream>>>(x, Wr, br, out, out + 65536, info, counts);
  k_prefix<<<1, 256, 0, stream>>>(counts, base, offs, t1s);
  k_scatter<<<NCH, 64, 0, stream>>>(info, base, tokl, gate, slots2);
  k_gather<<<NASN/4, 256, 0, stream>>>(x, tokl, Xg);
  k_gemm1<<<dim3(16, MAXT), 256, 0, stream>>>(Xg, W1b, b1, Hs, offs, t1s);
  k_gemm2<<<dim3(4, MAXT), 256, 0, stream>>>(Hs, W2b, b2, Ys, offs, t1s);
  k_combine<<<NTOK/4, 256, 0, stream>>>(Ys, info, slots2, out + 81920);
}

// Round 3
// 303.226 us; speedup vs baseline: 2.3752x; 1.0601x over previous
//
#include <hip/hip_runtime.h>
#include <hip/hip_bf16.h>

// Problem dims
#define NTOK 8192       // B*T
#define NASN 16384      // NTOK * K(=2)
#define C_ 512
#define H_ 2048
#define E_ 8
#define NCH 128         // token chunks for atomic spreading
#define CHTOK 64        // tokens per chunk
#define MAXT 136        // max total 128-row m-tiles

typedef __bf16 bf16x8 __attribute__((ext_vector_type(8)));
typedef float f32x4 __attribute__((ext_vector_type(4)));

// Workspace layout (bytes). Total ~118 MB.
#define WS_COUNTS 0                              // NCH*8*4 = 4096
#define WS_BASE   4096                           // NCH*8*4 = 4096
#define WS_OFFS   8192                           // 9*4 -> pad 256
#define WS_T1S    8448                           // 9*4 -> pad 256
#define WS_INFO   8704                           // NTOK*16
#define WS_TOKL   (WS_INFO + NTOK*16)            // NASN*4
#define WS_GATE   (WS_TOKL + NASN*4)             // NASN*4
#define WS_SLOTS  (WS_GATE + NASN*4)             // NTOK*8 (int2)
#define WS_XG     (WS_SLOTS + NTOK*8)            // NASN*C_*2 bf16 gathered X
#define WS_W1B    (WS_XG + (size_t)NASN*C_*2)    // E*H*C bf16, [e][h][c]
#define WS_W2B    (WS_W1B + (size_t)E_*H_*C_*2)  // E*C*H bf16, [e][c][h]
#define WS_HS     (WS_W2B + (size_t)E_*H_*C_*2)  // NASN*H bf16 hidden acts
// Ys (NASN*C_*4 = 33.55 MB) aliases Xg+W1b (both dead by k_gemm2).
#define WS_YS     WS_XG

__device__ __forceinline__ unsigned int f2bf(float f) {
  __hip_bfloat16 h = __float2bfloat16(f);
  return (unsigned int)*(unsigned short*)&h;
}

// async global->LDS, 16B per lane; LDS dest = wave-uniform base + lane*16
__device__ __forceinline__ void g2l16(const unsigned short* g, unsigned short* l) {
  __builtin_amdgcn_global_load_lds(
      (const __attribute__((address_space(1))) unsigned int*)g,
      (__attribute__((address_space(3))) unsigned int*)l, 16, 0, 0);
}

// ---------------- router: one wave per token, fp32 ----------------
__global__ __launch_bounds__(256) void k_router(
    const float* __restrict__ x, const float* __restrict__ Wr,
    const float* __restrict__ br, float* __restrict__ out_logits,
    float* __restrict__ out_idx, int4* __restrict__ info,
    int* __restrict__ counts)
{
  int t = blockIdx.x * 4 + (threadIdx.x >> 6);
  int lane = threadIdx.x & 63;
  const float4* xr = (const float4*)(x + (size_t)t * C_);
  float4 x0 = xr[lane*2], x1 = xr[lane*2+1];
  float xs[8] = {x0.x,x0.y,x0.z,x0.w,x1.x,x1.y,x1.z,x1.w};
  float acc[8] = {0,0,0,0,0,0,0,0};
  #pragma unroll
  for (int j = 0; j < 8; j++) {
    const float4* w = (const float4*)(Wr + (size_t)(lane*8+j) * E_);
    float4 w0 = w[0], w1 = w[1];
    float we[8] = {w0.x,w0.y,w0.z,w0.w,w1.x,w1.y,w1.z,w1.w};
    #pragma unroll
    for (int e = 0; e < 8; e++) acc[e] += xs[j] * we[e];
  }
  #pragma unroll
  for (int off = 1; off < 64; off <<= 1) {
    #pragma unroll
    for (int e = 0; e < 8; e++) acc[e] += __shfl_xor(acc[e], off, 64);
  }
  #pragma unroll
  for (int e = 0; e < 8; e++) acc[e] += br[e];
  if (lane == 0) {
    #pragma unroll
    for (int e = 0; e < 8; e++) out_logits[t*8 + e] = acc[e];
    int i0 = 0; float v0 = acc[0];
    #pragma unroll
    for (int e = 1; e < 8; e++) if (acc[e] > v0) { v0 = acc[e]; i0 = e; }
    int i1 = -1; float v1 = -1e30f;
    #pragma unroll
    for (int e = 0; e < 8; e++) if (e != i0 && acc[e] > v1) { v1 = acc[e]; i1 = e; }
    float d = expf(v1 - v0);
    float s1 = d / (1.0f + d);
    float s0 = 1.0f - s1;
    out_idx[t*2]     = (float)i0;
    out_idx[t*2 + 1] = (float)i1;
    info[t] = make_int4(i0, i1, __float_as_int(s0), __float_as_int(s1));
    int ch = t >> 6;
    atomicAdd(&counts[ch*8 + i0], 1);
    atomicAdd(&counts[ch*8 + i1], 1);
  }
}

// ---------------- prefix: per-chunk/per-expert slot bases ----------------
__global__ __launch_bounds__(256) void k_prefix(
    const int* __restrict__ counts, int* __restrict__ base,
    int* __restrict__ offs, int* __restrict__ t1s)
{
  __shared__ int lc[NCH*8];
  __shared__ int tot[8];
  __shared__ int off_s[9];
  int tid = threadIdx.x;
  for (int i = tid; i < NCH*8; i += 256) lc[i] = counts[i];
  __syncthreads();
  if (tid < 8) {
    int run = 0;
    for (int c = 0; c < NCH; c++) { int v = lc[c*8+tid]; lc[c*8+tid] = run; run += v; }
    tot[tid] = run;
  }
  __syncthreads();
  if (tid == 0) {
    int o = 0, t = 0;
    off_s[0] = 0; offs[0] = 0; t1s[0] = 0;
    for (int e = 0; e < 8; e++) {
      o += tot[e];
      off_s[e+1] = o; offs[e+1] = o;
      t += (tot[e] + 127) >> 7;
      t1s[e+1] = t;
    }
  }
  __syncthreads();
  for (int i = tid; i < NCH*8; i += 256) base[i] = off_s[i & 7] + lc[i];
}

// ---------------- scatter: chunk-local LDS rank -> slots ----------------
__global__ __launch_bounds__(64) void k_scatter(
    const int4* __restrict__ info, const int* __restrict__ base,
    int* __restrict__ tokl, float* __restrict__ gate, int2* __restrict__ slots2)
{
  __shared__ int cur[8];
  int c = blockIdx.x, tid = threadIdx.x;
  if (tid < 8) cur[tid] = base[c*8 + tid];
  __syncthreads();
  int t = c * CHTOK + tid;
  int4 nfo = info[t];
  int r0 = atomicAdd(&cur[nfo.x], 1);
  int r1 = atomicAdd(&cur[nfo.y], 1);
  tokl[r0] = t; gate[r0] = __int_as_float(nfo.z);
  tokl[r1] = t; gate[r1] = __int_as_float(nfo.w);
  slots2[t] = make_int2(r0, r1);
}

// ---------------- gather: x rows -> bf16 Xg rows, one wave per row ----------------
__global__ __launch_bounds__(256) void k_gather(
    const float* __restrict__ x, const int* __restrict__ tokl,
    unsigned short* __restrict__ Xg)
{
  int slot = blockIdx.x * 4 + (threadIdx.x >> 6);
  int lane = threadIdx.x & 63;
  int t = tokl[slot];
  const float4* xr = (const float4*)(x + (size_t)t * C_);
  float4 x0 = xr[lane*2], x1 = xr[lane*2+1];
  uint4 pk;
  pk.x = f2bf(x0.x) | (f2bf(x0.y) << 16);
  pk.y = f2bf(x0.z) | (f2bf(x0.w) << 16);
  pk.z = f2bf(x1.x) | (f2bf(x1.y) << 16);
  pk.w = f2bf(x1.z) | (f2bf(x1.w) << 16);
  *(uint4*)(Xg + (size_t)slot * C_ + lane*8) = pk;
}

// ---------------- weight transpose fp32[R][S] -> bf16[S][R] ----------------
__global__ __launch_bounds__(256) void k_transpose(
    const float* __restrict__ in, unsigned short* __restrict__ outp, int R, int S)
{
  __shared__ float tile[32][33];
  size_t zo = (size_t)blockIdx.z * R * S;
  in += zo; outp += zo;
  int s0 = blockIdx.x * 32, r0 = blockIdx.y * 32;
  int tx = threadIdx.x, ty = threadIdx.y;
  #pragma unroll
  for (int i = 0; i < 4; i++)
    tile[ty + i*8][tx] = in[(size_t)(r0 + ty + i*8) * S + s0 + tx];
  __syncthreads();
  #pragma unroll
  for (int i = 0; i < 4; i++)
    outp[(size_t)(s0 + ty + i*8) * R + r0 + tx] = f2bf(tile[tx][ty + i*8]);
}

// ---------------- grouped GEMM layer 1: Hs = relu(Xg @ W1 + b1) ----------------
// 128x128 tile, BK=64, global_load_lds staging with XOR-swizzled LDS layout.
__global__ __launch_bounds__(256) void k_gemm1(
    const unsigned short* __restrict__ Xg, const unsigned short* __restrict__ W1b,
    const float* __restrict__ b1, unsigned short* __restrict__ Hs,
    const int* __restrict__ offs, const int* __restrict__ t1s)
{
  __shared__ __align__(16) unsigned short AB[2*128*64];   // 32 KB
  unsigned short* Al = AB;
  unsigned short* Bl = AB + 128*64;
  int mt = blockIdx.y;
  if (mt >= t1s[8]) return;
  int e = 0;
  #pragma unroll
  for (int i = 0; i < 7; i++) if (mt >= t1s[e+1]) e++;
  int row0 = offs[e] + (mt - t1s[e]) * 128;
  int rowEnd = offs[e+1];
  int n0 = blockIdx.x * 128;
  int tid = threadIdx.x, lane = tid & 63, w = tid >> 6;
  int wm = (w & 1) * 64, wn = (w >> 1) * 64;
  int quad = lane >> 4, l16 = lane & 15;
  const f32x4 zero = {0.f, 0.f, 0.f, 0.f};
  f32x4 acc[4][4];
  #pragma unroll
  for (int i = 0; i < 4; i++)
    #pragma unroll
    for (int j = 0; j < 4; j++) acc[i][j] = zero;
  const unsigned short* Bsrc = W1b + ((size_t)e * H_ + n0) * C_;

  // staging geometry: instr (w*4+j) covers chunks L = (w*4+j)*64 + lane.
  // LDS chunk L holds global chunk (L&7) ^ (row&7) of row L>>3.
  const unsigned short* ga[4]; const unsigned short* gb[4];
  unsigned short* la[4]; unsigned short* lb[4];
  #pragma unroll
  for (int j = 0; j < 4; j++) {
    int L = (w*4 + j)*64 + lane;
    int row = L >> 3;
    int cc = (L & 7) ^ (row & 7);
    int gr = row0 + row; gr = gr < NASN-1 ? gr : NASN-1;
    ga[j] = Xg + (size_t)gr * C_ + cc*8;
    gb[j] = Bsrc + (size_t)row * C_ + cc*8;
    la[j] = Al + (w*4 + j)*512;
    lb[j] = Bl + (w*4 + j)*512;
  }
  int r7 = l16 & 7;

  for (int kk = 0; kk < C_; kk += 64) {
    #pragma unroll
    for (int j = 0; j < 4; j++) {
      g2l16(ga[j] + kk, la[j]);
      g2l16(gb[j] + kk, lb[j]);
    }
    __syncthreads();
    #pragma unroll
    for (int ks4 = 0; ks4 < 8; ks4 += 4) {
      int chunk = (ks4 + quad) ^ r7;
      bf16x8 af[4], bfr[4];
      #pragma unroll
      for (int i = 0; i < 4; i++)
        af[i] = *(const bf16x8*)&Al[(wm + i*16 + l16)*64 + chunk*8];
      #pragma unroll
      for (int j = 0; j < 4; j++)
        bfr[j] = *(const bf16x8*)&Bl[(wn + j*16 + l16)*64 + chunk*8];
      #pragma unroll
      for (int i = 0; i < 4; i++)
        #pragma unroll
        for (int j = 0; j < 4; j++)
          acc[i][j] = __builtin_amdgcn_mfma_f32_16x16x32_bf16(af[i], bfr[j], acc[i][j], 0, 0, 0);
    }
    __syncthreads();
  }

  // epilogue: per-wave LDS transpose -> coalesced 16B stores
  unsigned short* Lt = AB + w*4096;   // 64x64 bf16 per wave
  #pragma unroll
  for (int j = 0; j < 4; j++) {
    int n = n0 + wn + j*16 + l16;
    float bias = b1[e * H_ + n];
    #pragma unroll
    for (int i = 0; i < 4; i++)
      #pragma unroll
      for (int r = 0; r < 4; r++) {
        float v = acc[i][j][r] + bias;
        Lt[(i*16 + quad*4 + r)*64 + j*16 + l16] = (unsigned short)f2bf(v > 0.f ? v : 0.f);
      }
  }
  #pragma unroll
  for (int it = 0; it < 8; it++) {
    int rloc = it*8 + (lane >> 3);
    int m = row0 + wm + rloc;
    uint4 vv = *(uint4*)&Lt[rloc*64 + (lane & 7)*8];
    if (m < rowEnd)
      *(uint4*)(Hs + (size_t)m * H_ + n0 + wn + (lane & 7)*8) = vv;
  }
}

// ---------------- grouped GEMM layer 2: Ys = Hs @ W2 + b2 ----------------
__global__ __launch_bounds__(256) void k_gemm2(
    const unsigned short* __restrict__ Hs, const unsigned short* __restrict__ W2b,
    const float* __restrict__ b2, float* __restrict__ Ys,
    const int* __restrict__ offs, const int* __restrict__ t1s)
{
  __shared__ __align__(16) unsigned short AB[2*128*64];
  unsigned short* Al = AB;
  unsigned short* Bl = AB + 128*64;
  int mt = blockIdx.y;
  if (mt >= t1s[8]) return;
  int e = 0;
  #pragma unroll
  for (int i = 0; i < 7; i++) if (mt >= t1s[e+1]) e++;
  int row0 = offs[e] + (mt - t1s[e]) * 128;
  int rowEnd = offs[e+1];
  int n0 = blockIdx.x * 128;
  int tid = threadIdx.x, lane = tid & 63, w = tid >> 6;
  int wm = (w & 1) * 64, wn = (w >> 1) * 64;
  int quad = lane >> 4, l16 = lane & 15;
  const f32x4 zero = {0.f, 0.f, 0.f, 0.f};
  f32x4 acc[4][4];
  #pragma unroll
  for (int i = 0; i < 4; i++)
    #pragma unroll
    for (int j = 0; j < 4; j++) acc[i][j] = zero;
  const unsigned short* Bsrc = W2b + ((size_t)e * C_ + n0) * H_;

  const unsigned short* ga[4]; const unsigned short* gb[4];
  unsigned short* la[4]; unsigned short* lb[4];
  #pragma unroll
  for (int j = 0; j < 4; j++) {
    int L = (w*4 + j)*64 + lane;
    int row = L >> 3;
    int cc = (L & 7) ^ (row & 7);
    int gr = row0 + row; gr = gr < NASN-1 ? gr : NASN-1;
    ga[j] = Hs + (size_t)gr * H_ + cc*8;
    gb[j] = Bsrc + (size_t)row * H_ + cc*8;
    la[j] = Al + (w*4 + j)*512;
    lb[j] = Bl + (w*4 + j)*512;
  }
  int r7 = l16 & 7;

  for (int kk = 0; kk < H_; kk += 64) {
    #pragma unroll
    for (int j = 0; j < 4; j++) {
      g2l16(ga[j] + kk, la[j]);
      g2l16(gb[j] + kk, lb[j]);
    }
    __syncthreads();
    #pragma unroll
    for (int ks4 = 0; ks4 < 8; ks4 += 4) {
      int chunk = (ks4 + quad) ^ r7;
      bf16x8 af[4], bfr[4];
      #pragma unroll
      for (int i = 0; i < 4; i++)
        af[i] = *(const bf16x8*)&Al[(wm + i*16 + l16)*64 + chunk*8];
      #pragma unroll
      for (int j = 0; j < 4; j++)
        bfr[j] = *(const bf16x8*)&Bl[(wn + j*16 + l16)*64 + chunk*8];
      #pragma unroll
      for (int i = 0; i < 4; i++)
        #pragma unroll
        for (int j = 0; j < 4; j++)
          acc[i][j] = __builtin_amdgcn_mfma_f32_16x16x32_bf16(af[i], bfr[j], acc[i][j], 0, 0, 0);
    }
    __syncthreads();
  }

  // epilogue: fp32 LDS transpose in two 32-row halves (8 KB/wave each)
  float* Lt = (float*)AB + w*2048;
  #pragma unroll
  for (int h = 0; h < 2; h++) {
    #pragma unroll
    for (int j = 0; j < 4; j++) {
      int n = n0 + wn + j*16 + l16;
      float bias = b2[e * C_ + n];
      #pragma unroll
      for (int ii = 0; ii < 2; ii++) {
        int i = h*2 + ii;
        #pragma unroll
        for (int r = 0; r < 4; r++)
          Lt[(ii*16 + quad*4 + r)*64 + j*16 + l16] = acc[i][j][r] + bias;
      }
    }
    #pragma unroll
    for (int it = 0; it < 8; it++) {
      int rloc = it*4 + (lane >> 4);
      int m = row0 + wm + h*32 + rloc;
      float4 vv = *(float4*)&Lt[rloc*64 + (lane & 15)*4];
      if (m < rowEnd)
        *(float4*)(Ys + (size_t)m * C_ + n0 + wn + (lane & 15)*4) = vv;
    }
  }
}

// ---------------- combine: out[t] = g0*Ys[s0] + g1*Ys[s1] ----------------
__global__ __launch_bounds__(256) void k_combine(
    const float* __restrict__ Ys, const int4* __restrict__ info,
    const int2* __restrict__ slots2, float* __restrict__ outp)
{
  int t = blockIdx.x * 4 + (threadIdx.x >> 6);
  int lane = threadIdx.x & 63;
  int4 nfo = info[t];
  int2 ss = slots2[t];
  float g0 = __int_as_float(nfo.z), g1 = __int_as_float(nfo.w);
  const float4* ya = (const float4*)(Ys + (size_t)ss.x * C_);
  const float4* yb = (const float4*)(Ys + (size_t)ss.y * C_);
  float4* o = (float4*)(outp + (size_t)t * C_);
  #pragma unroll
  for (int i = 0; i < 2; i++) {
    float4 a = ya[lane*2 + i], b = yb[lane*2 + i];
    float4 r;
    r.x = g0*a.x + g1*b.x; r.y = g0*a.y + g1*b.y;
    r.z = g0*a.z + g1*b.z; r.w = g0*a.w + g1*b.w;
    o[lane*2 + i] = r;
  }
}

extern "C" void kernel_launch(void* const* d_in, const int* in_sizes, int n_in,
                              void* d_out, int out_size, void* d_ws, size_t ws_size,
                              hipStream_t stream)
{
  const float* x  = (const float*)d_in[0];
  const float* Wr = (const float*)d_in[1];
  const float* br = (const float*)d_in[2];
  const float* W1 = (const float*)d_in[3];
  const float* b1 = (const float*)d_in[4];
  const float* W2 = (const float*)d_in[5];
  const float* b2 = (const float*)d_in[6];
  float* out = (float*)d_out;   // [logits 65536 | idx 16384 | out 4194304]
  char* ws = (char*)d_ws;

  int*  counts = (int*)(ws + WS_COUNTS);
  int*  base   = (int*)(ws + WS_BASE);
  int*  offs   = (int*)(ws + WS_OFFS);
  int*  t1s    = (int*)(ws + WS_T1S);
  int4* info   = (int4*)(ws + WS_INFO);
  int*  tokl   = (int*)(ws + WS_TOKL);
  float* gate  = (float*)(ws + WS_GATE);
  int2* slots2 = (int2*)(ws + WS_SLOTS);
  unsigned short* Xg  = (unsigned short*)(ws + WS_XG);
  unsigned short* W1b = (unsigned short*)(ws + WS_W1B);
  unsigned short* W2b = (unsigned short*)(ws + WS_W2B);
  unsigned short* Hs  = (unsigned short*)(ws + WS_HS);
  float* Ys = (float*)(ws + WS_YS);   // aliases Xg+W1b (dead by gemm2)

  hipMemsetAsync(counts, 0, NCH*8*sizeof(int), stream);

  k_transpose<<<dim3(H_/32, C_/32, E_), dim3(32, 8), 0, stream>>>(W1, W1b, C_, H_);
  k_transpose<<<dim3(C_/32, H_/32, E_), dim3(32, 8), 0, stream>>>(W2, W2b, H_, C_);
  k_router<<<NTOK/4, 256, 0, stream>>>(x, Wr, br, out, out + 65536, info, counts);
  k_prefix<<<1, 256, 0, stream>>>(counts, base, offs, t1s);
  k_scatter<<<NCH, 64, 0, stream>>>(info, base, tokl, gate, slots2);
  k_gather<<<NASN/4, 256, 0, stream>>>(x, tokl, Xg);
  k_gemm1<<<dim3(16, MAXT), 256, 0, stream>>>(Xg, W1b, b1, Hs, offs, t1s);
  k_gemm2<<<dim3(4, MAXT), 256, 0, stream>>>(Hs, W2b, b2, Ys, offs, t1s);
  k_combine<<<NTOK/4, 256, 0, stream>>>(Ys, info, slots2, out + 81920);
}

// Round 4
// 300.516 us; speedup vs baseline: 2.3966x; 1.0090x over previous
//
#include <hip/hip_runtime.h>
#include <hip/hip_bf16.h>

// Problem dims
#define NTOK 8192       // B*T
#define NASN 16384      // NTOK * K(=2)
#define C_ 512
#define H_ 2048
#define E_ 8
#define NCH 128         // token chunks for atomic spreading
#define CHTOK 64        // tokens per chunk
#define MAXT 136        // max total 128-row m-tiles

typedef __bf16 bf16x8 __attribute__((ext_vector_type(8)));
typedef float f32x4 __attribute__((ext_vector_type(4)));

// Workspace layout (bytes). Total ~118 MB.
#define WS_COUNTS 0                              // NCH*8*4 = 4096
#define WS_BASE   4096                           // NCH*8*4 = 4096
#define WS_OFFS   8192                           // 9*4 -> pad 256
#define WS_T1S    8448                           // 9*4 -> pad 256
#define WS_INFO   8704                           // NTOK*16
#define WS_TOKL   (WS_INFO + NTOK*16)            // NASN*4
#define WS_GATE   (WS_TOKL + NASN*4)             // NASN*4
#define WS_SLOTS  (WS_GATE + NASN*4)             // NTOK*8 (int2)
#define WS_XG     (WS_SLOTS + NTOK*8)            // NASN*C_*2 bf16 gathered X
#define WS_W1B    (WS_XG + (size_t)NASN*C_*2)    // E*H*C bf16, [e][h][c]
#define WS_W2B    (WS_W1B + (size_t)E_*H_*C_*2)  // E*C*H bf16, [e][c][h]
#define WS_HS     (WS_W2B + (size_t)E_*H_*C_*2)  // NASN*H bf16 hidden acts
// Ys (NASN*C_*4 = 33.55 MB) aliases Xg+W1b (both dead by k_gemm2).
#define WS_YS     WS_XG

__device__ __forceinline__ unsigned int f2bf(float f) {
  __hip_bfloat16 h = __float2bfloat16(f);
  return (unsigned int)*(unsigned short*)&h;
}

// async global->LDS, 16B per lane; LDS dest = wave-uniform base + lane*16
__device__ __forceinline__ void g2l16(const unsigned short* g, unsigned short* l) {
  __builtin_amdgcn_global_load_lds(
      (const __attribute__((address_space(1))) unsigned int*)g,
      (__attribute__((address_space(3))) unsigned int*)l, 16, 0, 0);
}

// ---------------- router: one wave per token, fp32 ----------------
__global__ __launch_bounds__(256) void k_router(
    const float* __restrict__ x, const float* __restrict__ Wr,
    const float* __restrict__ br, float* __restrict__ out_logits,
    float* __restrict__ out_idx, int4* __restrict__ info,
    int* __restrict__ counts)
{
  int t = blockIdx.x * 4 + (threadIdx.x >> 6);
  int lane = threadIdx.x & 63;
  const float4* xr = (const float4*)(x + (size_t)t * C_);
  float4 x0 = xr[lane*2], x1 = xr[lane*2+1];
  float xs[8] = {x0.x,x0.y,x0.z,x0.w,x1.x,x1.y,x1.z,x1.w};
  float acc[8] = {0,0,0,0,0,0,0,0};
  #pragma unroll
  for (int j = 0; j < 8; j++) {
    const float4* w = (const float4*)(Wr + (size_t)(lane*8+j) * E_);
    float4 w0 = w[0], w1 = w[1];
    float we[8] = {w0.x,w0.y,w0.z,w0.w,w1.x,w1.y,w1.z,w1.w};
    #pragma unroll
    for (int e = 0; e < 8; e++) acc[e] += xs[j] * we[e];
  }
  #pragma unroll
  for (int off = 1; off < 64; off <<= 1) {
    #pragma unroll
    for (int e = 0; e < 8; e++) acc[e] += __shfl_xor(acc[e], off, 64);
  }
  #pragma unroll
  for (int e = 0; e < 8; e++) acc[e] += br[e];
  if (lane == 0) {
    #pragma unroll
    for (int e = 0; e < 8; e++) out_logits[t*8 + e] = acc[e];
    int i0 = 0; float v0 = acc[0];
    #pragma unroll
    for (int e = 1; e < 8; e++) if (acc[e] > v0) { v0 = acc[e]; i0 = e; }
    int i1 = -1; float v1 = -1e30f;
    #pragma unroll
    for (int e = 0; e < 8; e++) if (e != i0 && acc[e] > v1) { v1 = acc[e]; i1 = e; }
    float d = expf(v1 - v0);
    float s1 = d / (1.0f + d);
    float s0 = 1.0f - s1;
    out_idx[t*2]     = (float)i0;
    out_idx[t*2 + 1] = (float)i1;
    info[t] = make_int4(i0, i1, __float_as_int(s0), __float_as_int(s1));
    int ch = t >> 6;
    atomicAdd(&counts[ch*8 + i0], 1);
    atomicAdd(&counts[ch*8 + i1], 1);
  }
}

// ---------------- prefix: per-chunk/per-expert slot bases ----------------
__global__ __launch_bounds__(256) void k_prefix(
    const int* __restrict__ counts, int* __restrict__ base,
    int* __restrict__ offs, int* __restrict__ t1s)
{
  __shared__ int lc[NCH*8];
  __shared__ int tot[8];
  __shared__ int off_s[9];
  int tid = threadIdx.x;
  for (int i = tid; i < NCH*8; i += 256) lc[i] = counts[i];
  __syncthreads();
  if (tid < 8) {
    int run = 0;
    for (int c = 0; c < NCH; c++) { int v = lc[c*8+tid]; lc[c*8+tid] = run; run += v; }
    tot[tid] = run;
  }
  __syncthreads();
  if (tid == 0) {
    int o = 0, t = 0;
    off_s[0] = 0; offs[0] = 0; t1s[0] = 0;
    for (int e = 0; e < 8; e++) {
      o += tot[e];
      off_s[e+1] = o; offs[e+1] = o;
      t += (tot[e] + 127) >> 7;
      t1s[e+1] = t;
    }
  }
  __syncthreads();
  for (int i = tid; i < NCH*8; i += 256) base[i] = off_s[i & 7] + lc[i];
}

// ---------------- scatter: chunk-local LDS rank -> slots ----------------
__global__ __launch_bounds__(64) void k_scatter(
    const int4* __restrict__ info, const int* __restrict__ base,
    int* __restrict__ tokl, float* __restrict__ gate, int2* __restrict__ slots2)
{
  __shared__ int cur[8];
  int c = blockIdx.x, tid = threadIdx.x;
  if (tid < 8) cur[tid] = base[c*8 + tid];
  __syncthreads();
  int t = c * CHTOK + tid;
  int4 nfo = info[t];
  int r0 = atomicAdd(&cur[nfo.x], 1);
  int r1 = atomicAdd(&cur[nfo.y], 1);
  tokl[r0] = t; gate[r0] = __int_as_float(nfo.z);
  tokl[r1] = t; gate[r1] = __int_as_float(nfo.w);
  slots2[t] = make_int2(r0, r1);
}

// ---------------- gather: x rows -> bf16 Xg rows, one wave per row ----------------
__global__ __launch_bounds__(256) void k_gather(
    const float* __restrict__ x, const int* __restrict__ tokl,
    unsigned short* __restrict__ Xg)
{
  int slot = blockIdx.x * 4 + (threadIdx.x >> 6);
  int lane = threadIdx.x & 63;
  int t = tokl[slot];
  const float4* xr = (const float4*)(x + (size_t)t * C_);
  float4 x0 = xr[lane*2], x1 = xr[lane*2+1];
  uint4 pk;
  pk.x = f2bf(x0.x) | (f2bf(x0.y) << 16);
  pk.y = f2bf(x0.z) | (f2bf(x0.w) << 16);
  pk.z = f2bf(x1.x) | (f2bf(x1.y) << 16);
  pk.w = f2bf(x1.z) | (f2bf(x1.w) << 16);
  *(uint4*)(Xg + (size_t)slot * C_ + lane*8) = pk;
}

// ---------------- weight transpose fp32[R][S] -> bf16[S][R] ----------------
__global__ __launch_bounds__(256) void k_transpose(
    const float* __restrict__ in, unsigned short* __restrict__ outp, int R, int S)
{
  __shared__ float tile[32][33];
  size_t zo = (size_t)blockIdx.z * R * S;
  in += zo; outp += zo;
  int s0 = blockIdx.x * 32, r0 = blockIdx.y * 32;
  int tx = threadIdx.x, ty = threadIdx.y;
  #pragma unroll
  for (int i = 0; i < 4; i++)
    tile[ty + i*8][tx] = in[(size_t)(r0 + ty + i*8) * S + s0 + tx];
  __syncthreads();
  #pragma unroll
  for (int i = 0; i < 4; i++)
    outp[(size_t)(s0 + ty + i*8) * R + r0 + tx] = f2bf(tile[tx][ty + i*8]);
}

// ---------------- grouped GEMM layer 1: Hs = relu(Xg @ W1 + b1) ----------------
// 128x128 tile, BK=64, global_load_lds staging with XOR-swizzled LDS layout.
__global__ __launch_bounds__(256) void k_gemm1(
    const unsigned short* __restrict__ Xg, const unsigned short* __restrict__ W1b,
    const float* __restrict__ b1, unsigned short* __restrict__ Hs,
    const int* __restrict__ offs, const int* __restrict__ t1s)
{
  __shared__ __align__(16) unsigned short AB[2*128*64];   // 32 KB
  unsigned short* Al = AB;
  unsigned short* Bl = AB + 128*64;
  int mt = blockIdx.y;
  if (mt >= t1s[8]) return;
  int e = 0;
  #pragma unroll
  for (int i = 0; i < 7; i++) if (mt >= t1s[e+1]) e++;
  int row0 = offs[e] + (mt - t1s[e]) * 128;
  int rowEnd = offs[e+1];
  int n0 = blockIdx.x * 128;
  int tid = threadIdx.x, lane = tid & 63, w = tid >> 6;
  int wm = (w & 1) * 64, wn = (w >> 1) * 64;
  int quad = lane >> 4, l16 = lane & 15;
  const f32x4 zero = {0.f, 0.f, 0.f, 0.f};
  f32x4 acc[4][4];
  #pragma unroll
  for (int i = 0; i < 4; i++)
    #pragma unroll
    for (int j = 0; j < 4; j++) acc[i][j] = zero;
  const unsigned short* Bsrc = W1b + ((size_t)e * H_ + n0) * C_;

  // staging geometry: instr (w*4+j) covers chunks L = (w*4+j)*64 + lane.
  // LDS chunk L holds global chunk (L&7) ^ (row&7) of row L>>3.
  const unsigned short* ga[4]; const unsigned short* gb[4];
  unsigned short* la[4]; unsigned short* lb[4];
  #pragma unroll
  for (int j = 0; j < 4; j++) {
    int L = (w*4 + j)*64 + lane;
    int row = L >> 3;
    int cc = (L & 7) ^ (row & 7);
    int gr = row0 + row; gr = gr < NASN-1 ? gr : NASN-1;
    ga[j] = Xg + (size_t)gr * C_ + cc*8;
    gb[j] = Bsrc + (size_t)row * C_ + cc*8;
    la[j] = Al + (w*4 + j)*512;
    lb[j] = Bl + (w*4 + j)*512;
  }
  int r7 = l16 & 7;

  for (int kk = 0; kk < C_; kk += 64) {
    #pragma unroll
    for (int j = 0; j < 4; j++) {
      g2l16(ga[j] + kk, la[j]);
      g2l16(gb[j] + kk, lb[j]);
    }
    __syncthreads();
    #pragma unroll
    for (int ks4 = 0; ks4 < 8; ks4 += 4) {
      int chunk = (ks4 + quad) ^ r7;
      bf16x8 af[4], bfr[4];
      #pragma unroll
      for (int i = 0; i < 4; i++)
        af[i] = *(const bf16x8*)&Al[(wm + i*16 + l16)*64 + chunk*8];
      #pragma unroll
      for (int j = 0; j < 4; j++)
        bfr[j] = *(const bf16x8*)&Bl[(wn + j*16 + l16)*64 + chunk*8];
      #pragma unroll
      for (int i = 0; i < 4; i++)
        #pragma unroll
        for (int j = 0; j < 4; j++)
          acc[i][j] = __builtin_amdgcn_mfma_f32_16x16x32_bf16(af[i], bfr[j], acc[i][j], 0, 0, 0);
    }
    __syncthreads();
  }

  // epilogue: per-wave LDS transpose -> coalesced 16B stores
  unsigned short* Lt = AB + w*4096;   // 64x64 bf16 per wave
  #pragma unroll
  for (int j = 0; j < 4; j++) {
    int n = n0 + wn + j*16 + l16;
    float bias = b1[e * H_ + n];
    #pragma unroll
    for (int i = 0; i < 4; i++)
      #pragma unroll
      for (int r = 0; r < 4; r++) {
        float v = acc[i][j][r] + bias;
        Lt[(i*16 + quad*4 + r)*64 + j*16 + l16] = (unsigned short)f2bf(v > 0.f ? v : 0.f);
      }
  }
  #pragma unroll
  for (int it = 0; it < 8; it++) {
    int rloc = it*8 + (lane >> 3);
    int m = row0 + wm + rloc;
    uint4 vv = *(uint4*)&Lt[rloc*64 + (lane & 7)*8];
    if (m < rowEnd)
      *(uint4*)(Hs + (size_t)m * H_ + n0 + wn + (lane & 7)*8) = vv;
  }
}

// ---------------- grouped GEMM layer 2: Ys = Hs @ W2 + b2 ----------------
// AITER-style pipelined K-loop: LDS double buffer (2x32KB), raw s_barrier,
// s_waitcnt vmcnt(8) (never 0 mid-loop) so next tile's 8 global_load_lds
// stay in flight across both barriers. gemm2 is grid-limited to ~2 blocks/CU,
// so the 64KB LDS costs no occupancy.
__global__ __launch_bounds__(256) void k_gemm2(
    const unsigned short* __restrict__ Hs, const unsigned short* __restrict__ W2b,
    const float* __restrict__ b2, float* __restrict__ Ys,
    const int* __restrict__ offs, const int* __restrict__ t1s)
{
  __shared__ __align__(16) unsigned short AB[2*2*128*64];   // 64 KB, 2 buffers
  int mt = blockIdx.y;
  if (mt >= t1s[8]) return;
  int e = 0;
  #pragma unroll
  for (int i = 0; i < 7; i++) if (mt >= t1s[e+1]) e++;
  int row0 = offs[e] + (mt - t1s[e]) * 128;
  int rowEnd = offs[e+1];
  int n0 = blockIdx.x * 128;
  int tid = threadIdx.x, lane = tid & 63, w = tid >> 6;
  int wm = (w & 1) * 64, wn = (w >> 1) * 64;
  int quad = lane >> 4, l16 = lane & 15;
  const f32x4 zero = {0.f, 0.f, 0.f, 0.f};
  f32x4 acc[4][4];
  #pragma unroll
  for (int i = 0; i < 4; i++)
    #pragma unroll
    for (int j = 0; j < 4; j++) acc[i][j] = zero;
  const unsigned short* Bsrc = W2b + ((size_t)e * C_ + n0) * H_;

  const unsigned short* ga[4]; const unsigned short* gb[4];
  unsigned short* la[4]; unsigned short* lb[4];
  #pragma unroll
  for (int j = 0; j < 4; j++) {
    int L = (w*4 + j)*64 + lane;
    int row = L >> 3;
    int cc = (L & 7) ^ (row & 7);
    int gr = row0 + row; gr = gr < NASN-1 ? gr : NASN-1;
    ga[j] = Hs + (size_t)gr * H_ + cc*8;
    gb[j] = Bsrc + (size_t)row * H_ + cc*8;
    la[j] = AB + (w*4 + j)*512;            // A slice in buffer 0
    lb[j] = AB + 8192 + (w*4 + j)*512;     // B slice in buffer 0
  }
  int r7 = l16 & 7;
  const int KI = H_ / 64;                  // 32 iterations

  // prologue: stage iter 0 into buffer 0
  #pragma unroll
  for (int j = 0; j < 4; j++) { g2l16(ga[j], la[j]); g2l16(gb[j], lb[j]); }

  for (int ki = 0; ki < KI; ki++) {
    int p = ki & 1;
    if (ki + 1 < KI) {
      int off = (ki + 1) * 64;
      int bo = (p ^ 1) * 16384;
      #pragma unroll
      for (int j = 0; j < 4; j++) {
        g2l16(ga[j] + off, la[j] + bo);
        g2l16(gb[j] + off, lb[j] + bo);
      }
      // wait for current buffer's 8 loads (older); next 8 stay in flight
      asm volatile("s_waitcnt vmcnt(8)" ::: "memory");
    } else {
      asm volatile("s_waitcnt vmcnt(0)" ::: "memory");
    }
    asm volatile("s_barrier" ::: "memory");   // buf p ready for all waves

    const unsigned short* Ap = AB + p*16384;
    const unsigned short* Bp = AB + p*16384 + 8192;
    #pragma unroll
    for (int ks4 = 0; ks4 < 8; ks4 += 4) {
      int chunk = (ks4 + quad) ^ r7;
      bf16x8 af[4], bfr[4];
      #pragma unroll
      for (int i = 0; i < 4; i++)
        af[i] = *(const bf16x8*)&Ap[(wm + i*16 + l16)*64 + chunk*8];
      #pragma unroll
      for (int j = 0; j < 4; j++)
        bfr[j] = *(const bf16x8*)&Bp[(wn + j*16 + l16)*64 + chunk*8];
      #pragma unroll
      for (int i = 0; i < 4; i++)
        #pragma unroll
        for (int j = 0; j < 4; j++)
          acc[i][j] = __builtin_amdgcn_mfma_f32_16x16x32_bf16(af[i], bfr[j], acc[i][j], 0, 0, 0);
    }
    // all my ds_reads retired (MFMA consumed them); signal buf p reusable
    asm volatile("s_waitcnt lgkmcnt(0)" ::: "memory");
    asm volatile("s_barrier" ::: "memory");
  }

  // epilogue: fp32 LDS transpose in two 32-row halves (8 KB/wave each)
  float* Lt = (float*)AB + w*2048;
  #pragma unroll
  for (int h = 0; h < 2; h++) {
    #pragma unroll
    for (int j = 0; j < 4; j++) {
      int n = n0 + wn + j*16 + l16;
      float bias = b2[e * C_ + n];
      #pragma unroll
      for (int ii = 0; ii < 2; ii++) {
        int i = h*2 + ii;
        #pragma unroll
        for (int r = 0; r < 4; r++)
          Lt[(ii*16 + quad*4 + r)*64 + j*16 + l16] = acc[i][j][r] + bias;
      }
    }
    __syncthreads();
    #pragma unroll
    for (int it = 0; it < 8; it++) {
      int rloc = it*4 + (lane >> 4);
      int m = row0 + wm + h*32 + rloc;
      float4 vv = *(float4*)&Lt[rloc*64 + (lane & 15)*4];
      if (m < rowEnd)
        *(float4*)(Ys + (size_t)m * C_ + n0 + wn + (lane & 15)*4) = vv;
    }
    __syncthreads();
  }
}

// ---------------- combine: out[t] = g0*Ys[s0] + g1*Ys[s1] ----------------
__global__ __launch_bounds__(256) void k_combine(
    const float* __restrict__ Ys, const int4* __restrict__ info,
    const int2* __restrict__ slots2, float* __restrict__ outp)
{
  int t = blockIdx.x * 4 + (threadIdx.x >> 6);
  int lane = threadIdx.x & 63;
  int4 nfo = info[t];
  int2 ss = slots2[t];
  float g0 = __int_as_float(nfo.z), g1 = __int_as_float(nfo.w);
  const float4* ya = (const float4*)(Ys + (size_t)ss.x * C_);
  const float4* yb = (const float4*)(Ys + (size_t)ss.y * C_);
  float4* o = (float4*)(outp + (size_t)t * C_);
  #pragma unroll
  for (int i = 0; i < 2; i++) {
    float4 a = ya[lane*2 + i], b = yb[lane*2 + i];
    float4 r;
    r.x = g0*a.x + g1*b.x; r.y = g0*a.y + g1*b.y;
    r.z = g0*a.z + g1*b.z; r.w = g0*a.w + g1*b.w;
    o[lane*2 + i] = r;
  }
}

extern "C" void kernel_launch(void* const* d_in, const int* in_sizes, int n_in,
                              void* d_out, int out_size, void* d_ws, size_t ws_size,
                              hipStream_t stream)
{
  const float* x  = (const float*)d_in[0];
  const float* Wr = (const float*)d_in[1];
  const float* br = (const float*)d_in[2];
  const float* W1 = (const float*)d_in[3];
  const float* b1 = (const float*)d_in[4];
  const float* W2 = (const float*)d_in[5];
  const float* b2 = (const float*)d_in[6];
  float* out = (float*)d_out;   // [logits 65536 | idx 16384 | out 4194304]
  char* ws = (char*)d_ws;

  int*  counts = (int*)(ws + WS_COUNTS);
  int*  base   = (int*)(ws + WS_BASE);
  int*  offs   = (int*)(ws + WS_OFFS);
  int*  t1s    = (int*)(ws + WS_T1S);
  int4* info   = (int4*)(ws + WS_INFO);
  int*  tokl   = (int*)(ws + WS_TOKL);
  float* gate  = (float*)(ws + WS_GATE);
  int2* slots2 = (int2*)(ws + WS_SLOTS);
  unsigned short* Xg  = (unsigned short*)(ws + WS_XG);
  unsigned short* W1b = (unsigned short*)(ws + WS_W1B);
  unsigned short* W2b = (unsigned short*)(ws + WS_W2B);
  unsigned short* Hs  = (unsigned short*)(ws + WS_HS);
  float* Ys = (float*)(ws + WS_YS);   // aliases Xg+W1b (dead by gemm2)

  hipMemsetAsync(counts, 0, NCH*8*sizeof(int), stream);

  k_transpose<<<dim3(H_/32, C_/32, E_), dim3(32, 8), 0, stream>>>(W1, W1b, C_, H_);
  k_transpose<<<dim3(C_/32, H_/32, E_), dim3(32, 8), 0, stream>>>(W2, W2b, H_, C_);
  k_router<<<NTOK/4, 256, 0, stream>>>(x, Wr, br, out, out + 65536, info, counts);
  k_prefix<<<1, 256, 0, stream>>>(counts, base, offs, t1s);
  k_scatter<<<NCH, 64, 0, stream>>>(info, base, tokl, gate, slots2);
  k_gather<<<NASN/4, 256, 0, stream>>>(x, tokl, Xg);
  k_gemm1<<<dim3(16, MAXT), 256, 0, stream>>>(Xg, W1b, b1, Hs, offs, t1s);
  k_gemm2<<<dim3(4, MAXT), 256, 0, stream>>>(Hs, W2b, b2, Ys, offs, t1s);
  k_combine<<<NTOK/4, 256, 0, stream>>>(Ys, info, slots2, out + 81920);
}